// Round 9
// baseline (7802.433 us; speedup 1.0000x reference)
//
#include <hip/hip_runtime.h>
#include <hip/hip_bf16.h>

#define NN 2048
#define BB 8
#define NC 64
#define NTILE 64   // K-tiles of 32
#define NITER 32   // 2 K-tiles per main-loop iteration

typedef __bf16 bf16_8 __attribute__((ext_vector_type(8)));
typedef __bf16 bf16_4 __attribute__((ext_vector_type(4)));
typedef float f32x16 __attribute__((ext_vector_type(16)));

__device__ __forceinline__ void gll16(const void* g, void* l) {
  __builtin_amdgcn_global_load_lds((const __attribute__((address_space(1))) void*)g,
                                   (__attribute__((address_space(3))) void*)l,
                                   16, 0, 0);
}

// fp32 -> bf16 convert + transpose, 16B/lane global reads. (unchanged)
__global__ __launch_bounds__(256)
void k_convert(const float* __restrict__ A, __bf16* __restrict__ Ab, __bf16* __restrict__ At) {
  __shared__ __bf16 tile[64][65];
  int b = blockIdx.z;
  const float* Asrc = A + (size_t)b * NN * NN;
  __bf16* Abd = Ab + (size_t)b * NN * NN;
  __bf16* Atd = At + (size_t)b * NN * NN;
  int r0 = blockIdx.y * 64, c0 = blockIdx.x * 64;
  int row = threadIdx.x >> 4;          // 0..15
  int col4 = (threadIdx.x & 15) * 4;   // 0..60
#pragma unroll
  for (int rr = 0; rr < 64; rr += 16) {
    float4 v = *(const float4*)&Asrc[(size_t)(r0 + row + rr) * NN + c0 + col4];
    bf16_4 hv;
    hv[0] = (__bf16)v.x; hv[1] = (__bf16)v.y; hv[2] = (__bf16)v.z; hv[3] = (__bf16)v.w;
    *(bf16_4*)&Abd[(size_t)(r0 + row + rr) * NN + c0 + col4] = hv;
    tile[row + rr][col4 + 0] = hv[0];
    tile[row + rr][col4 + 1] = hv[1];
    tile[row + rr][col4 + 2] = hv[2];
    tile[row + rr][col4 + 3] = hv[3];
  }
  __syncthreads();
  int row2 = threadIdx.x >> 3;         // 0..31
  int col8 = (threadIdx.x & 7) * 8;    // 0..56
#pragma unroll
  for (int rr = 0; rr < 64; rr += 32) {
    bf16_8 v;
#pragma unroll
    for (int j = 0; j < 8; ++j) v[j] = tile[col8 + j][row2 + rr];
    *(bf16_8*)&Atd[(size_t)(c0 + row2 + rr) * NN + r0 + col8] = v;
  }
}

// C[m,n] = sum_k P[m,k]*Q[n,k], one batch. 256x256 tile, BK=32 (r9: halves
// LDS to 64 KiB -> 2 blocks/CU; m114 mechanism: cross-block TLP fills the
// lockstep barrier bubbles that pinned MfmaUtil at ~42% for 1 block/CU).
// 8 waves (wm=wave>>2, wn=wave&3), 32x32x16 MFMA.
// Read swizzle g(r)=(r>>2)&3 over 4 chunks/row (16-lane group covers all
// 32 8B banks: bank = (r%4)*8 + 2*(c^g(r)) + half -- conflict-free, same
// criterion validated in r4). Two-phase X/Y K-tile schedule (r5/r6):
//   X(t): read A-h0(4) B0(2) B1(2) from buf b; stage A-h1(t+1)->buf b^1 (1);
//         8 MFMA acc[0..1][*]; sched_barrier(0); s_barrier
//   Y(t): read A-h1(4) from buf b; stage A0,B0,B1(t+2)->buf b (3);
//         8 MFMA acc[2..3][*]; vmcnt(3); sched_barrier(0); s_barrier
// vmcnt(3) leaves Y's own 3 in flight, drains X(t)'s 1 -> tile t+1 landed.
__device__ __forceinline__
void gemm_body256(const __bf16* __restrict__ Pb, const __bf16* __restrict__ Qb,
                  __bf16* __restrict__ Cb, __bf16* __restrict__ Ctb,
                  __bf16* smem, int tmBlk, int tnBlk) {
  __bf16 (*As)[256][32] = (__bf16(*)[256][32])smem;            // 2 x 16 KB
  __bf16 (*Bs)[256][32] = (__bf16(*)[256][32])(smem + 16384);  // 2 x 16 KB
  const int tid = threadIdx.x;
  const int wave = tid >> 6, lane = tid & 63;
  const int wm = wave >> 2, wn = wave & 3;
  const int tm = tmBlk * 256, tn = tnBlk * 256;
  const int am = lane & 31, ah = lane >> 5;
  const int rx = (am >> 2) & 3;   // read-side swizzle g(row)=(row>>2)&3

  // staging: each region = 128 rows x 32 cols = 8 KB; wave covers 16 rows
  // (1 KB = 1 gll16). Lane l -> row base+wave*16+(l>>2), physical chunk l&3
  // holding logical chunk (l&3) ^ g(row); g(row) = ((wave*16+(l>>2))>>2)&3
  // = (l>>4)&3 (wave*4 == 0 mod 4).
  const int sr = lane >> 2;
  const int sc = (lane & 3) ^ ((lane >> 4) & 3);
  const __bf16* srcA = Pb + (size_t)(tm + wave * 16 + sr) * NN + sc * 8;
  const __bf16* srcB = Qb + (size_t)(tn + wave * 16 + sr) * NN + sc * 8;

#define STAGE(Tc_, s_, bufT_)                                                  \
  do {                                                                         \
    if ((s_) == 0) { /* A h0 */                                                \
      gll16(srcA + (size_t)(Tc_) * 32, &As[bufT_][wave * 16][0]);              \
    } else if ((s_) == 1) { /* B h1 */                                         \
      gll16(srcB + (size_t)128 * NN + (size_t)(Tc_) * 32,                      \
            &Bs[bufT_][128 + wave * 16][0]);                                   \
    } else if ((s_) == 2) { /* A h1 */                                         \
      gll16(srcA + (size_t)128 * NN + (size_t)(Tc_) * 32,                      \
            &As[bufT_][128 + wave * 16][0]);                                   \
    } else { /* B h0 */                                                        \
      gll16(srcB + (size_t)(Tc_) * 32, &Bs[bufT_][wave * 16][0]);              \
    }                                                                          \
  } while (0)

  // prologue: tile0 full (4 loads), tile1 A0/B0/B1 (3 loads).
  STAGE(0, 0, 0); STAGE(0, 3, 0); STAGE(0, 1, 0); STAGE(0, 2, 0);
  STAGE(1, 0, 1); STAGE(1, 3, 1); STAGE(1, 1, 1);
  asm volatile("s_waitcnt vmcnt(3)" ::: "memory");
  __builtin_amdgcn_s_barrier();

  f32x16 acc[4][2] = {};
  bf16_8 af[2][2], bfr[2][2];

  for (int it = 0; it < NITER; ++it) {
#pragma unroll
    for (int h = 0; h < 2; ++h) {     // K-tile t = 2*it + h, buf b = h
      const int b = h;
      // ================= X phase =================
#pragma unroll
      for (int ks = 0; ks < 2; ++ks) {
        const int ra = (0 * 2 + wm) * 32 + am;   // im=0 rows
        af[0][ks] = *(const bf16_8*)&As[b][ra][((2 * ks + ah) ^ rx) * 8];
      }
#pragma unroll
      for (int ks = 0; ks < 2; ++ks) {
        const int rb0 = wn * 32 + am;
        bfr[0][ks] = *(const bf16_8*)&Bs[b][rb0][((2 * ks + ah) ^ rx) * 8];
      }
#pragma unroll
      for (int ks = 0; ks < 2; ++ks) {
        const int ra = (1 * 2 + wm) * 32 + am;   // im=1 rows
        af[1][ks] = *(const bf16_8*)&As[b][ra][((2 * ks + ah) ^ rx) * 8];
      }
#pragma unroll
      for (int ks = 0; ks < 2; ++ks) {
        const int rb1 = (4 + wn) * 32 + am;
        bfr[1][ks] = *(const bf16_8*)&Bs[b][rb1][((2 * ks + ah) ^ rx) * 8];
      }
      // stage: A-h1 of tile t+1 -> other buffer (last read Y(t-1))
      {
        int T = 2 * it + h + 1; if (T > NTILE - 1) T = NTILE - 1;
        STAGE(T, 2, b ^ 1);
      }
      __builtin_amdgcn_s_setprio(1);
#pragma unroll
      for (int ks = 0; ks < 2; ++ks) {
#pragma unroll
        for (int i = 0; i < 2; ++i) {
          acc[i][0] = __builtin_amdgcn_mfma_f32_32x32x16_bf16(
              af[i][ks], bfr[0][ks], acc[i][0], 0, 0, 0);
          acc[i][1] = __builtin_amdgcn_mfma_f32_32x32x16_bf16(
              af[i][ks], bfr[1][ks], acc[i][1], 0, 0, 0);
        }
      }
      __builtin_amdgcn_s_setprio(0);
      __builtin_amdgcn_sched_barrier(0);
      __builtin_amdgcn_s_barrier();
      // ================= Y phase =================
#pragma unroll
      for (int i = 0; i < 2; ++i) {
        const int ra = (4 + 2 * i + wm) * 32 + am;
#pragma unroll
        for (int ks = 0; ks < 2; ++ks)
          af[i][ks] = *(const bf16_8*)&As[b][ra][((2 * ks + ah) ^ rx) * 8];
      }
      // stage: A-h0/B-h0/B-h1 of tile t+2 -> this buffer (last read X(t))
      {
        int T = 2 * it + h + 2; if (T > NTILE - 1) T = NTILE - 1;
        STAGE(T, 0, b); STAGE(T, 3, b); STAGE(T, 1, b);
      }
      __builtin_amdgcn_s_setprio(1);
#pragma unroll
      for (int ks = 0; ks < 2; ++ks) {
#pragma unroll
        for (int i = 0; i < 2; ++i) {
          acc[2 + i][1] = __builtin_amdgcn_mfma_f32_32x32x16_bf16(
              af[i][ks], bfr[1][ks], acc[2 + i][1], 0, 0, 0);
          acc[2 + i][0] = __builtin_amdgcn_mfma_f32_32x32x16_bf16(
              af[i][ks], bfr[0][ks], acc[2 + i][0], 0, 0, 0);
        }
      }
      __builtin_amdgcn_s_setprio(0);
      asm volatile("s_waitcnt vmcnt(3)" ::: "memory");
      __builtin_amdgcn_sched_barrier(0);
      __builtin_amdgcn_s_barrier();
    }
  }
  asm volatile("s_waitcnt vmcnt(0) lgkmcnt(0)" ::: "memory");  // drain dummies

  // C/D layout (32x32): col = lane&31, row = (reg&3) + 8*(reg>>2) + 4*(lane>>5)
  const int cc = am;
  const int rq = ah * 4;
  if (Cb != nullptr) {
#pragma unroll
    for (int im = 0; im < 4; ++im)
#pragma unroll
      for (int in = 0; in < 2; ++in)
#pragma unroll
        for (int reg = 0; reg < 16; ++reg) {
          int row = (reg & 3) + 8 * (reg >> 2) + rq;
          Cb[(size_t)(tm + (2 * im + wm) * 32 + row) * NN +
             (tn + (4 * in + wn) * 32 + cc)] = (__bf16)acc[im][in][reg];
        }
  }

  if (Ctb != nullptr) {
    __syncthreads();
    __bf16 (*Tt)[264] = (__bf16(*)[264])smem;       // 64 x 264 x 2B = 33.8 KB
#pragma unroll
    for (int ch = 0; ch < 4; ++ch) {
      // chunk ch = C cols [ch*64, +64): writers have wn>>1 == ch&1, in = ch>>1
      if ((wn >> 1) == (ch & 1)) {
        const int inw = ch >> 1;
#pragma unroll
        for (int im = 0; im < 4; ++im)
#pragma unroll
          for (int g = 0; g < 4; ++g) {
            bf16_4 v;
#pragma unroll
            for (int r = 0; r < 4; ++r) v[r] = (__bf16)acc[im][inw][g * 4 + r];
            *(bf16_4*)&Tt[(wn & 1) * 32 + cc][(2 * im + wm) * 32 + 8 * g + rq] = v;
          }
      }
      __syncthreads();
#pragma unroll
      for (int rr = 0; rr < 4; ++rr) {
        int trow = rr * 16 + (tid >> 5);
        int tcol = (tid & 31) * 8;
        bf16_8 v = *(const bf16_8*)&Tt[trow][tcol];
        *(bf16_8*)&Ctb[(size_t)(tn + ch * 64 + trow) * NN + tm + tcol] = v;
      }
      __syncthreads();
    }
  }
#undef STAGE
}

// XCD-aware chunked swizzle (T1, r6: FETCH 590->197 MB).

// G1: A2 = A @ A, dual-write (A2, A2t). 512 blocks at 2 blocks/CU = ONE
// clean pass; XCD r owns batch r.
__global__ __launch_bounds__(512, 4)
void k_gemm1(const __bf16* __restrict__ Ab, const __bf16* __restrict__ At,
             __bf16* __restrict__ A2, __bf16* __restrict__ A2t) {
  __shared__ __align__(16) __bf16 smem[32768];  // 64 KB static
  int lid = ((int)blockIdx.z * gridDim.y + blockIdx.y) * gridDim.x + blockIdx.x;
  int swz = (lid & 7) * 64 + (lid >> 3);        // 512 blocks
  int bz = swz >> 6, ty = (swz >> 3) & 7, tx = swz & 7;
  size_t mb = (size_t)bz * NN * NN;
  gemm_body256(Ab + mb, At + mb, A2 + mb, A2t + mb, smem, ty, tx);
}

// G2+G3 merged (r6 wiring): job0: A3t = At @ A2^T (scalar-C path);
// job1: A4 = A2 @ A2 dual-write (A4, A4t=alias Ab, dead after G1).
// 1024 blocks = 2 passes at 2 blocks/CU; XCD r owns batches 2r, 2r+1.
__global__ __launch_bounds__(512, 4)
void k_gemm23(const __bf16* __restrict__ At, const __bf16* __restrict__ A2,
              const __bf16* __restrict__ A2t,
              __bf16* __restrict__ A3t, __bf16* __restrict__ A4,
              __bf16* __restrict__ A4t) {
  __shared__ __align__(16) __bf16 smem[32768];  // 64 KB static
  int lid = ((int)blockIdx.z * gridDim.y + blockIdx.y) * gridDim.x + blockIdx.x;
  int swz = (lid & 7) * 128 + (lid >> 3);       // 1024 blocks
  int bz = swz >> 6, ty = (swz >> 3) & 7, tx = swz & 7;
  int job = bz >> 3;
  size_t mb = (size_t)(bz & 7) * NN * NN;
  if (job == 0)
    gemm_body256(At + mb, A2 + mb, A3t + mb, nullptr, smem, ty, tx);
  else
    gemm_body256(A2 + mb, A2t + mb, A4 + mb, A4t + mb, smem, ty, tx);
}

// One wave per row n. d5=rowdot(A2,A3t), d6=rowdot(A2,A4t),
// d7=rowdot(A4,A3t), d8=rowdot(A4,A4t). d1..d4 free diagonal reads. (r6)
__global__ __launch_bounds__(256)
void k_reduce(const float* __restrict__ A, const float* __restrict__ h,
              const __bf16* __restrict__ A2, const __bf16* __restrict__ A3t,
              const __bf16* __restrict__ A4, const __bf16* __restrict__ A4t,
              float* __restrict__ out) {
  int b = blockIdx.y;
  int wave = threadIdx.x >> 6, lane = threadIdx.x & 63;
  int n = blockIdx.x * 4 + wave;
  size_t mb = (size_t)b * NN * NN;
  size_t rb = mb + (size_t)n * NN;
  float d5 = 0, d6 = 0, d7 = 0, d8 = 0;
  for (int c = 0; c < NN; c += 512) {
    int k = c + lane * 8;
    bf16_8 va2  = *(const bf16_8*)(A2 + rb + k);
    bf16_8 va3t = *(const bf16_8*)(A3t + rb + k);
    bf16_8 va4  = *(const bf16_8*)(A4 + rb + k);
    bf16_8 va4t = *(const bf16_8*)(A4t + rb + k);
#pragma unroll
    for (int j = 0; j < 8; ++j) {
      float f2 = (float)va2[j], f4 = (float)va4[j];
      float f3t = (float)va3t[j], f4t = (float)va4t[j];
      d5 += f2 * f3t;
      d6 += f2 * f4t;
      d7 += f4 * f3t;
      d8 += f4 * f4t;
    }
  }
#pragma unroll
  for (int off = 32; off > 0; off >>= 1) {
    d5 += __shfl_xor(d5, off);
    d6 += __shfl_xor(d6, off);
    d7 += __shfl_xor(d7, off);
    d8 += __shfl_xor(d8, off);
  }
  float d1 = A[mb + (size_t)n * NN + n];
  float d2 = (float)A2[rb + n];
  float d3 = (float)A3t[rb + n];
  float d4 = (float)A4[rb + n];
  float r = h[lane] + h[64 + lane] * d1 + h[128 + lane] * d2 + h[192 + lane] * d3 +
            h[256 + lane] * d4 + h[320 + lane] * d5 + h[384 + lane] * d6 +
            h[448 + lane] * d7 + h[512 + lane] * d8;
  out[((size_t)b * NN + n) * NC + lane] = r;
}

extern "C" void kernel_launch(void* const* d_in, const int* in_sizes, int n_in,
                              void* d_out, int out_size, void* d_ws, size_t ws_size,
                              hipStream_t stream) {
  const float* A = (const float*)d_in[0];
  const float* h = (const float*)d_in[1];
  float* out = (float*)d_out;

  size_t elems = (size_t)BB * NN * NN;  // 64 MiB per bf16 buffer
  __bf16* Ab  = (__bf16*)d_ws;
  __bf16* At  = Ab + elems;
  __bf16* A2  = At + elems;
  __bf16* A2t = A2 + elems;
  __bf16* A3t = A2t + elems;
  __bf16* A4  = A3t + elems;
  __bf16* A4t = Ab;  // alias: Ab dead after G1 (total ws: 6 x 64 MiB)

  // A -> bf16 + transpose
  k_convert<<<dim3(32, 32, BB), dim3(256), 0, stream>>>(A, Ab, At);
  // A2 = A @ A  (dual-write)
  k_gemm1<<<dim3(8, 8, BB), dim3(512), 0, stream>>>(Ab, At, A2, A2t);
  // A3t = (A^3)^T and A4 = A2 @ A2 (+A4t) in one dispatch
  k_gemm23<<<dim3(8, 8, 2 * BB), dim3(512), 0, stream>>>(At, A2, A2t, A3t, A4, A4t);
  // diagonals + channel combine
  k_reduce<<<dim3(NN / 4, BB), dim3(256), 0, stream>>>(A, h, A2, A3t, A4, A4t, out);
}

// Round 10
// 717.363 us; speedup vs baseline: 10.8766x; 10.8766x over previous
//
#include <hip/hip_runtime.h>
#include <hip/hip_bf16.h>

#define NN 2048
#define BB 8
#define NC 64
#define NTILE 32   // K-tiles of 64
#define NITER 16   // 2 K-tiles per main-loop iteration

typedef __bf16 bf16_8 __attribute__((ext_vector_type(8)));
typedef __bf16 bf16_4 __attribute__((ext_vector_type(4)));
typedef float f32x16 __attribute__((ext_vector_type(16)));

__device__ __forceinline__ void gll16(const void* g, void* l) {
  __builtin_amdgcn_global_load_lds((const __attribute__((address_space(1))) void*)g,
                                   (__attribute__((address_space(3))) void*)l,
                                   16, 0, 0);
}

// fp32 -> bf16 convert + transpose, 16B/lane global reads. (unchanged)
__global__ __launch_bounds__(256)
void k_convert(const float* __restrict__ A, __bf16* __restrict__ Ab, __bf16* __restrict__ At) {
  __shared__ __bf16 tile[64][65];
  int b = blockIdx.z;
  const float* Asrc = A + (size_t)b * NN * NN;
  __bf16* Abd = Ab + (size_t)b * NN * NN;
  __bf16* Atd = At + (size_t)b * NN * NN;
  int r0 = blockIdx.y * 64, c0 = blockIdx.x * 64;
  int row = threadIdx.x >> 4;          // 0..15
  int col4 = (threadIdx.x & 15) * 4;   // 0..60
#pragma unroll
  for (int rr = 0; rr < 64; rr += 16) {
    float4 v = *(const float4*)&Asrc[(size_t)(r0 + row + rr) * NN + c0 + col4];
    bf16_4 hv;
    hv[0] = (__bf16)v.x; hv[1] = (__bf16)v.y; hv[2] = (__bf16)v.z; hv[3] = (__bf16)v.w;
    *(bf16_4*)&Abd[(size_t)(r0 + row + rr) * NN + c0 + col4] = hv;
    tile[row + rr][col4 + 0] = hv[0];
    tile[row + rr][col4 + 1] = hv[1];
    tile[row + rr][col4 + 2] = hv[2];
    tile[row + rr][col4 + 3] = hv[3];
  }
  __syncthreads();
  int row2 = threadIdx.x >> 3;         // 0..31
  int col8 = (threadIdx.x & 7) * 8;    // 0..56
#pragma unroll
  for (int rr = 0; rr < 64; rr += 32) {
    bf16_8 v;
#pragma unroll
    for (int j = 0; j < 8; ++j) v[j] = tile[col8 + j][row2 + rr];
    *(bf16_8*)&Atd[(size_t)(c0 + row2 + rr) * NN + r0 + col8] = v;
  }
}

// C[m,n] = sum_k P[m,k]*Q[n,k], one batch. r10: 128x128 tile, 4 waves
// (wm=wave>>1 owns 64 rows, wn=wave&1 owns 64 cols; 64x64/wave ->
// acc[2][2] f32x16 = 64 VGPR), BK=64, LDS 64 KiB -> 2 blocks/CU (m114:
// cross-block TLP fills lockstep barrier bubbles; r9 failed from a
// launch-bounds VGPR cap, not the mechanism). 32x32x16 MFMA.
// Read swizzle g(r)=(r>>1)&7 (r4-validated, conflict-free).
// Regions (each read in exactly ONE phase):
//   A-even = rows [0,32)+[64,96)  (frag0 of both wm)   read in X
//   A-odd  = rows [32,64)+[96,128) (frag1)             read in Y
//   B-lo   = rows [0,64), B-hi = rows [64,128)         read in X (reg-cached)
// Two-phase K-tile schedule (r6 counts carry over verbatim):
//   X(t): read A-even(4) B-lo(4) B-hi(4); stage A-odd(t+1)->buf^1 (2/wave);
//         8 MFMA acc[0][*]; sched_barrier(0); s_barrier
//   Y(t): read A-odd(4); stage A-even,B-lo,B-hi(t+2)->buf (6/wave);
//         8 MFMA acc[1][*]; vmcnt(6); sched_barrier(0); s_barrier
// vmcnt(6) leaves Y's own 6 in flight, drains X(t)'s 2 -> tile t+1 landed.
__device__ __forceinline__
void gemm_body128(const __bf16* __restrict__ Pb, const __bf16* __restrict__ Qb,
                  __bf16* __restrict__ Cb, __bf16* __restrict__ Ctb,
                  __bf16* smem, int tmBlk, int tnBlk) {
  __bf16 (*As)[128][64] = (__bf16(*)[128][64])smem;            // 2 x 16 KB
  __bf16 (*Bs)[128][64] = (__bf16(*)[128][64])(smem + 16384);  // 2 x 16 KB
  const int tid = threadIdx.x;
  const int wave = tid >> 6, lane = tid & 63;
  const int wm = wave >> 1, wn = wave & 1;
  const int tm = tmBlk * 128, tn = tnBlk * 128;
  const int am = lane & 31, ah = lane >> 5;
  const int rx = (am >> 1) & 7;   // read-side swizzle g(row)=(row>>1)&7

  // staging: every gll16 covers 8 rows x 64 cols (1 KB); lane l -> row
  // base+(l>>3), physical chunk l&7 holding logical chunk (l&7)^g(row).
  // All bases (w*8, 32+w*8, 64+w*8, 96+w*8) are == (wave&1)*8 mod 16, so
  // g(row) = (wave&1)*4 + (lane>>4) -- same formula as r6.
  const int sr = lane >> 3;
  const int sc = (lane & 7) ^ (((wave & 1) * 4 + (lane >> 4)) & 7);
  const __bf16* srcA = Pb + (size_t)(tm + wave * 8 + sr) * NN + sc * 8;
  const __bf16* srcB = Qb + (size_t)(tn + wave * 8 + sr) * NN + sc * 8;

#define STAGE(Tc_, s_, bufT_)                                                  \
  do {                                                                         \
    if ((s_) == 0) { /* A-even: frag0 rows of both wm */                       \
      const __bf16* s0 = srcA + (size_t)(Tc_) * 64;                            \
      gll16(s0,                   &As[bufT_][wave * 8][0]);                    \
      gll16(s0 + (size_t)64 * NN, &As[bufT_][64 + wave * 8][0]);               \
    } else if ((s_) == 1) { /* B-hi: rows [64,128) */                          \
      const __bf16* s0 = srcB + (size_t)64 * NN + (size_t)(Tc_) * 64;          \
      gll16(s0,                   &Bs[bufT_][64 + wave * 8][0]);               \
      gll16(s0 + (size_t)32 * NN, &Bs[bufT_][96 + wave * 8][0]);               \
    } else if ((s_) == 2) { /* A-odd: frag1 rows */                            \
      const __bf16* s0 = srcA + (size_t)32 * NN + (size_t)(Tc_) * 64;          \
      gll16(s0,                   &As[bufT_][32 + wave * 8][0]);               \
      gll16(s0 + (size_t)64 * NN, &As[bufT_][96 + wave * 8][0]);               \
    } else { /* B-lo: rows [0,64) */                                           \
      const __bf16* s0 = srcB + (size_t)(Tc_) * 64;                            \
      gll16(s0,                   &Bs[bufT_][wave * 8][0]);                    \
      gll16(s0 + (size_t)32 * NN, &Bs[bufT_][32 + wave * 8][0]);               \
    }                                                                          \
  } while (0)

  // prologue: tile0 full (8 loads/wave), tile1 A-even/B-lo/B-hi (6 loads).
  STAGE(0, 0, 0); STAGE(0, 3, 0); STAGE(0, 1, 0); STAGE(0, 2, 0);
  STAGE(1, 0, 1); STAGE(1, 3, 1); STAGE(1, 1, 1);
  asm volatile("s_waitcnt vmcnt(6)" ::: "memory");
  __builtin_amdgcn_s_barrier();

  f32x16 acc[2][2] = {};
  bf16_8 af[4], bfr[2][4];

  for (int it = 0; it < NITER; ++it) {
#pragma unroll
    for (int h = 0; h < 2; ++h) {     // K-tile t = 2*it + h, buf b = h
      const int b = h;
      // ================= X phase =================
      {
        const int ra = wm * 64 + am;            // frag0 rows
#pragma unroll
        for (int ks = 0; ks < 4; ++ks)
          af[ks] = *(const bf16_8*)&As[b][ra][((2 * ks + ah) ^ rx) * 8];
      }
      {
        const int rb0 = wn * 64 + am;           // n-frag 0
#pragma unroll
        for (int ks = 0; ks < 4; ++ks)
          bfr[0][ks] = *(const bf16_8*)&Bs[b][rb0][((2 * ks + ah) ^ rx) * 8];
        const int rb1 = wn * 64 + 32 + am;      // n-frag 1
#pragma unroll
        for (int ks = 0; ks < 4; ++ks)
          bfr[1][ks] = *(const bf16_8*)&Bs[b][rb1][((2 * ks + ah) ^ rx) * 8];
      }
      // stage: A-odd of tile t+1 -> other buffer (last read Y(t-1))
      {
        int T = 2 * it + h + 1; if (T > NTILE - 1) T = NTILE - 1;
        STAGE(T, 2, b ^ 1);
      }
      __builtin_amdgcn_s_setprio(1);
#pragma unroll
      for (int ks = 0; ks < 4; ++ks) {
        acc[0][0] = __builtin_amdgcn_mfma_f32_32x32x16_bf16(
            af[ks], bfr[0][ks], acc[0][0], 0, 0, 0);
        acc[0][1] = __builtin_amdgcn_mfma_f32_32x32x16_bf16(
            af[ks], bfr[1][ks], acc[0][1], 0, 0, 0);
      }
      __builtin_amdgcn_s_setprio(0);
      __builtin_amdgcn_sched_barrier(0);
      __builtin_amdgcn_s_barrier();
      // ================= Y phase =================
      {
        const int ra = wm * 64 + 32 + am;       // frag1 rows
#pragma unroll
        for (int ks = 0; ks < 4; ++ks)
          af[ks] = *(const bf16_8*)&As[b][ra][((2 * ks + ah) ^ rx) * 8];
      }
      // stage: A-even/B-lo/B-hi of tile t+2 -> this buffer (last read X(t))
      {
        int T = 2 * it + h + 2; if (T > NTILE - 1) T = NTILE - 1;
        STAGE(T, 0, b); STAGE(T, 3, b); STAGE(T, 1, b);
      }
      __builtin_amdgcn_s_setprio(1);
#pragma unroll
      for (int ks = 0; ks < 4; ++ks) {
        acc[1][1] = __builtin_amdgcn_mfma_f32_32x32x16_bf16(
            af[ks], bfr[1][ks], acc[1][1], 0, 0, 0);
        acc[1][0] = __builtin_amdgcn_mfma_f32_32x32x16_bf16(
            af[ks], bfr[0][ks], acc[1][0], 0, 0, 0);
      }
      __builtin_amdgcn_s_setprio(0);
      asm volatile("s_waitcnt vmcnt(6)" ::: "memory");
      __builtin_amdgcn_sched_barrier(0);
      __builtin_amdgcn_s_barrier();
    }
  }
  asm volatile("s_waitcnt vmcnt(0) lgkmcnt(0)" ::: "memory");  // drain dummies

  // C/D layout (32x32): col = lane&31, row = (reg&3) + 8*(reg>>2) + 4*(lane>>5)
  const int cc = am;
  const int rq = ah * 4;
  if (Cb != nullptr) {
#pragma unroll
    for (int i = 0; i < 2; ++i)
#pragma unroll
      for (int j = 0; j < 2; ++j)
#pragma unroll
        for (int reg = 0; reg < 16; ++reg) {
          int row = (reg & 3) + 8 * (reg >> 2) + rq;
          Cb[(size_t)(tm + wm * 64 + i * 32 + row) * NN +
             (tn + wn * 64 + j * 32 + cc)] = (__bf16)acc[i][j][reg];
        }
  }

  if (Ctb != nullptr) {
    __syncthreads();
    __bf16 (*Tt)[136] = (__bf16(*)[136])smem;   // 64 x 136 x 2B = 17 KB
#pragma unroll
    for (int ch = 0; ch < 2; ++ch) {
      // chunk ch = C cols [ch*64, +64): writers are the 2 waves with wn==ch
      if (wn == ch) {
#pragma unroll
        for (int i = 0; i < 2; ++i)
#pragma unroll
          for (int j = 0; j < 2; ++j)
#pragma unroll
            for (int g = 0; g < 4; ++g) {
              bf16_4 v;
#pragma unroll
              for (int r = 0; r < 4; ++r) v[r] = (__bf16)acc[i][j][g * 4 + r];
              *(bf16_4*)&Tt[j * 32 + cc][wm * 64 + i * 32 + 8 * g + rq] = v;
            }
      }
      __syncthreads();
#pragma unroll
      for (int p = 0; p < 4; ++p) {
        int trow = p * 16 + (tid >> 4);         // 0..63
        int tcol = (tid & 15) * 8;              // 0..120
        bf16_8 v = *(const bf16_8*)&Tt[trow][tcol];
        *(bf16_8*)&Ctb[(size_t)(tn + ch * 64 + trow) * NN + tm + tcol] = v;
      }
      __syncthreads();
    }
  }
#undef STAGE
}

// XCD-aware chunked swizzle (T1). G1: 2048 blocks, XCD r owns batch r's
// 256 tiles (16x16). G23: 4096 blocks, XCD r owns batches 2r, 2r+1.

// G1: A2 = A @ A, dual-write (A2, A2t). 2048 blocks at 2 blocks/CU = 4
// clean passes.
__global__ __launch_bounds__(256, 2)
void k_gemm1(const __bf16* __restrict__ Ab, const __bf16* __restrict__ At,
             __bf16* __restrict__ A2, __bf16* __restrict__ A2t) {
  __shared__ __align__(16) __bf16 smem[32768];  // 64 KB static
  int lid = ((int)blockIdx.z * gridDim.y + blockIdx.y) * gridDim.x + blockIdx.x;
  int swz = (lid & 7) * 256 + (lid >> 3);       // 2048 blocks
  int bz = swz >> 8, ty = (swz >> 4) & 15, tx = swz & 15;
  size_t mb = (size_t)bz * NN * NN;
  gemm_body128(Ab + mb, At + mb, A2 + mb, A2t + mb, smem, ty, tx);
}

// G2+G3 merged (r6 wiring): job0: A3t = At @ A2^T (scalar-C path);
// job1: A4 = A2 @ A2 dual-write (A4, A4t=alias Ab, dead after G1).
// 4096 blocks = 8 passes at 2 blocks/CU.
__global__ __launch_bounds__(256, 2)
void k_gemm23(const __bf16* __restrict__ At, const __bf16* __restrict__ A2,
              const __bf16* __restrict__ A2t,
              __bf16* __restrict__ A3t, __bf16* __restrict__ A4,
              __bf16* __restrict__ A4t) {
  __shared__ __align__(16) __bf16 smem[32768];  // 64 KB static
  int lid = ((int)blockIdx.z * gridDim.y + blockIdx.y) * gridDim.x + blockIdx.x;
  int swz = (lid & 7) * 512 + (lid >> 3);       // 4096 blocks
  int bz = swz >> 8, ty = (swz >> 4) & 15, tx = swz & 15;
  int job = bz >> 3;
  size_t mb = (size_t)(bz & 7) * NN * NN;
  if (job == 0)
    gemm_body128(At + mb, A2 + mb, A3t + mb, nullptr, smem, ty, tx);
  else
    gemm_body128(A2 + mb, A2t + mb, A4 + mb, A4t + mb, smem, ty, tx);
}

// One wave per row n. d5=rowdot(A2,A3t), d6=rowdot(A2,A4t),
// d7=rowdot(A4,A3t), d8=rowdot(A4,A4t). d1..d4 free diagonal reads. (r6)
__global__ __launch_bounds__(256)
void k_reduce(const float* __restrict__ A, const float* __restrict__ h,
              const __bf16* __restrict__ A2, const __bf16* __restrict__ A3t,
              const __bf16* __restrict__ A4, const __bf16* __restrict__ A4t,
              float* __restrict__ out) {
  int b = blockIdx.y;
  int wave = threadIdx.x >> 6, lane = threadIdx.x & 63;
  int n = blockIdx.x * 4 + wave;
  size_t mb = (size_t)b * NN * NN;
  size_t rb = mb + (size_t)n * NN;
  float d5 = 0, d6 = 0, d7 = 0, d8 = 0;
  for (int c = 0; c < NN; c += 512) {
    int k = c + lane * 8;
    bf16_8 va2  = *(const bf16_8*)(A2 + rb + k);
    bf16_8 va3t = *(const bf16_8*)(A3t + rb + k);
    bf16_8 va4  = *(const bf16_8*)(A4 + rb + k);
    bf16_8 va4t = *(const bf16_8*)(A4t + rb + k);
#pragma unroll
    for (int j = 0; j < 8; ++j) {
      float f2 = (float)va2[j], f4 = (float)va4[j];
      float f3t = (float)va3t[j], f4t = (float)va4t[j];
      d5 += f2 * f3t;
      d6 += f2 * f4t;
      d7 += f4 * f3t;
      d8 += f4 * f4t;
    }
  }
#pragma unroll
  for (int off = 32; off > 0; off >>= 1) {
    d5 += __shfl_xor(d5, off);
    d6 += __shfl_xor(d6, off);
    d7 += __shfl_xor(d7, off);
    d8 += __shfl_xor(d8, off);
  }
  float d1 = A[mb + (size_t)n * NN + n];
  float d2 = (float)A2[rb + n];
  float d3 = (float)A3t[rb + n];
  float d4 = (float)A4[rb + n];
  float r = h[lane] + h[64 + lane] * d1 + h[128 + lane] * d2 + h[192 + lane] * d3 +
            h[256 + lane] * d4 + h[320 + lane] * d5 + h[384 + lane] * d6 +
            h[448 + lane] * d7 + h[512 + lane] * d8;
  out[((size_t)b * NN + n) * NC + lane] = r;
}

extern "C" void kernel_launch(void* const* d_in, const int* in_sizes, int n_in,
                              void* d_out, int out_size, void* d_ws, size_t ws_size,
                              hipStream_t stream) {
  const float* A = (const float*)d_in[0];
  const float* h = (const float*)d_in[1];
  float* out = (float*)d_out;

  size_t elems = (size_t)BB * NN * NN;  // 64 MiB per bf16 buffer
  __bf16* Ab  = (__bf16*)d_ws;
  __bf16* At  = Ab + elems;
  __bf16* A2  = At + elems;
  __bf16* A2t = A2 + elems;
  __bf16* A3t = A2t + elems;
  __bf16* A4  = A3t + elems;
  __bf16* A4t = Ab;  // alias: Ab dead after G1 (total ws: 6 x 64 MiB)

  // A -> bf16 + transpose
  k_convert<<<dim3(32, 32, BB), dim3(256), 0, stream>>>(A, Ab, At);
  // A2 = A @ A  (dual-write)
  k_gemm1<<<dim3(16, 16, BB), dim3(256), 0, stream>>>(Ab, At, A2, A2t);
  // A3t = (A^3)^T and A4 = A2 @ A2 (+A4t) in one dispatch
  k_gemm23<<<dim3(16, 16, 2 * BB), dim3(256), 0, stream>>>(At, A2, A2t, A3t, A4, A4t);
  // diagonals + channel combine
  k_reduce<<<dim3(NN / 4, BB), dim3(256), 0, stream>>>(A, h, A2, A3t, A4, A4t, out);
}

// Round 11
// 637.302 us; speedup vs baseline: 12.2429x; 1.1256x over previous
//
#include <hip/hip_runtime.h>
#include <hip/hip_bf16.h>

#define NN 2048
#define BB 8
#define NC 64
#define NTILE 32   // K-tiles of 64
#define NITER 16   // 2 K-tiles per main-loop iteration

typedef __bf16 bf16_8 __attribute__((ext_vector_type(8)));
typedef __bf16 bf16_4 __attribute__((ext_vector_type(4)));
typedef float f32x16 __attribute__((ext_vector_type(16)));

__device__ __forceinline__ void gll16(const void* g, void* l) {
  __builtin_amdgcn_global_load_lds((const __attribute__((address_space(1))) void*)g,
                                   (__attribute__((address_space(3))) void*)l,
                                   16, 0, 0);
}

// fp32 -> bf16 convert + transpose, 16B/lane global reads.
__global__ __launch_bounds__(256)
void k_convert(const float* __restrict__ A, __bf16* __restrict__ Ab, __bf16* __restrict__ At) {
  __shared__ __bf16 tile[64][65];
  int b = blockIdx.z;
  const float* Asrc = A + (size_t)b * NN * NN;
  __bf16* Abd = Ab + (size_t)b * NN * NN;
  __bf16* Atd = At + (size_t)b * NN * NN;
  int r0 = blockIdx.y * 64, c0 = blockIdx.x * 64;
  int row = threadIdx.x >> 4;          // 0..15
  int col4 = (threadIdx.x & 15) * 4;   // 0..60
#pragma unroll
  for (int rr = 0; rr < 64; rr += 16) {
    float4 v = *(const float4*)&Asrc[(size_t)(r0 + row + rr) * NN + c0 + col4];
    bf16_4 hv;
    hv[0] = (__bf16)v.x; hv[1] = (__bf16)v.y; hv[2] = (__bf16)v.z; hv[3] = (__bf16)v.w;
    *(bf16_4*)&Abd[(size_t)(r0 + row + rr) * NN + c0 + col4] = hv;
    tile[row + rr][col4 + 0] = hv[0];
    tile[row + rr][col4 + 1] = hv[1];
    tile[row + rr][col4 + 2] = hv[2];
    tile[row + rr][col4 + 3] = hv[3];
  }
  __syncthreads();
  int row2 = threadIdx.x >> 3;         // 0..31
  int col8 = (threadIdx.x & 7) * 8;    // 0..56
#pragma unroll
  for (int rr = 0; rr < 64; rr += 32) {
    bf16_8 v;
#pragma unroll
    for (int j = 0; j < 8; ++j) v[j] = tile[col8 + j][row2 + rr];
    *(bf16_8*)&Atd[(size_t)(c0 + row2 + rr) * NN + r0 + col8] = v;
  }
}

// C[m,n] = sum_k P[m,k]*Q[n,k], one batch. 256x256 tile, BK=64, 8 waves
// (wm=wave>>2, wn=wave&3), 32x32x16 MFMA. Static 128 KiB LDS.
// Chunk swizzle g(r)=(r>>1)&7 (r4: conflict-free, -98% SQ_LDS_BANK_CONFLICT).
// Two-phase K-tile schedule (r5/r6 — session optimum):
//   X(t): read A-h0(8) B0(4) B1(4) from buf b; stage A-h1(t+1)->buf b^1 (2);
//         16 MFMA acc[0..1][*]; sched_barrier(0); s_barrier
//   Y(t): read A-h1(8) from buf b; stage A0,B0,B1(t+2)->buf b (6);
//         16 MFMA acc[2..3][*]; vmcnt(6); sched_barrier(0); s_barrier
// vmcnt(6) leaves Y's own 6 in flight, drains X(t)'s 2 -> tile t+1 landed.
__device__ __forceinline__
void gemm_body256(const __bf16* __restrict__ Pb, const __bf16* __restrict__ Qb,
                  __bf16* __restrict__ Cb, __bf16* __restrict__ Ctb,
                  __bf16* smem, int tmBlk, int tnBlk) {
  __bf16 (*As)[256][64] = (__bf16(*)[256][64])smem;            // 2 x 32 KB
  __bf16 (*Bs)[256][64] = (__bf16(*)[256][64])(smem + 32768);  // 2 x 32 KB
  const int tid = threadIdx.x;
  const int wave = tid >> 6, lane = tid & 63;
  const int wm = wave >> 2, wn = wave & 3;
  const int tm = tmBlk * 256, tn = tnBlk * 256;
  const int am = lane & 31, ah = lane >> 5;
  const int rx = (am >> 1) & 7;   // read-side swizzle g(row)=(row>>1)&7

  const int sr = lane >> 3;
  const int sc = (lane & 7) ^ (((wave & 1) * 4 + (lane >> 4)) & 7);
  const __bf16* srcA = Pb + (size_t)(tm + wave * 8 + sr) * NN + sc * 8;
  const __bf16* srcB = Qb + (size_t)(tn + wave * 8 + sr) * NN + sc * 8;

#define STAGE(Tc_, s_, bufT_)                                                  \
  do {                                                                         \
    if ((s_) == 0) { /* A h0 */                                                \
      const __bf16* s0 = srcA + (size_t)(Tc_) * 64;                            \
      gll16(s0,                   &As[bufT_][wave * 8][0]);                    \
      gll16(s0 + (size_t)64 * NN, &As[bufT_][64 + wave * 8][0]);               \
    } else if ((s_) == 1) { /* B h1 */                                         \
      const __bf16* s0 = srcB + (size_t)128 * NN + (size_t)(Tc_) * 64;         \
      gll16(s0,                   &Bs[bufT_][128 + wave * 8][0]);              \
      gll16(s0 + (size_t)64 * NN, &Bs[bufT_][192 + wave * 8][0]);              \
    } else if ((s_) == 2) { /* A h1 */                                         \
      const __bf16* s0 = srcA + (size_t)128 * NN + (size_t)(Tc_) * 64;         \
      gll16(s0,                   &As[bufT_][128 + wave * 8][0]);              \
      gll16(s0 + (size_t)64 * NN, &As[bufT_][192 + wave * 8][0]);              \
    } else { /* B h0 */                                                        \
      const __bf16* s0 = srcB + (size_t)(Tc_) * 64;                            \
      gll16(s0,                   &Bs[bufT_][wave * 8][0]);                    \
      gll16(s0 + (size_t)64 * NN, &Bs[bufT_][64 + wave * 8][0]);               \
    }                                                                          \
  } while (0)

  // prologue: tile0 full (8 loads), tile1 A0/B0/B1 (6 loads).
  STAGE(0, 0, 0); STAGE(0, 3, 0); STAGE(0, 1, 0); STAGE(0, 2, 0);
  STAGE(1, 0, 1); STAGE(1, 3, 1); STAGE(1, 1, 1);
  asm volatile("s_waitcnt vmcnt(6)" ::: "memory");
  __builtin_amdgcn_s_barrier();

  f32x16 acc[4][2] = {};
  bf16_8 af[2][4], bfr[2][4];

  for (int it = 0; it < NITER; ++it) {
#pragma unroll
    for (int h = 0; h < 2; ++h) {     // K-tile t = 2*it + h, buf b = h
      const int b = h;
      // ================= X phase =================
#pragma unroll
      for (int ks = 0; ks < 4; ++ks) {
        const int ra = (0 * 2 + wm) * 32 + am;   // im=0 rows
        af[0][ks] = *(const bf16_8*)&As[b][ra][((2 * ks + ah) ^ rx) * 8];
      }
#pragma unroll
      for (int ks = 0; ks < 4; ++ks) {
        const int rb0 = wn * 32 + am;
        bfr[0][ks] = *(const bf16_8*)&Bs[b][rb0][((2 * ks + ah) ^ rx) * 8];
      }
#pragma unroll
      for (int ks = 0; ks < 4; ++ks) {
        const int ra = (1 * 2 + wm) * 32 + am;   // im=1 rows
        af[1][ks] = *(const bf16_8*)&As[b][ra][((2 * ks + ah) ^ rx) * 8];
      }
#pragma unroll
      for (int ks = 0; ks < 4; ++ks) {
        const int rb1 = (4 + wn) * 32 + am;
        bfr[1][ks] = *(const bf16_8*)&Bs[b][rb1][((2 * ks + ah) ^ rx) * 8];
      }
      // stage: A-h1 of tile t+1 -> other buffer (last read Y(t-1))
      {
        int T = 2 * it + h + 1; if (T > NTILE - 1) T = NTILE - 1;
        STAGE(T, 2, b ^ 1);
      }
      __builtin_amdgcn_s_setprio(1);
#pragma unroll
      for (int ks = 0; ks < 4; ++ks) {
#pragma unroll
        for (int i = 0; i < 2; ++i) {
          acc[i][0] = __builtin_amdgcn_mfma_f32_32x32x16_bf16(
              af[i][ks], bfr[0][ks], acc[i][0], 0, 0, 0);
          acc[i][1] = __builtin_amdgcn_mfma_f32_32x32x16_bf16(
              af[i][ks], bfr[1][ks], acc[i][1], 0, 0, 0);
        }
      }
      __builtin_amdgcn_s_setprio(0);
      __builtin_amdgcn_sched_barrier(0);
      __builtin_amdgcn_s_barrier();
      // ================= Y phase =================
#pragma unroll
      for (int i = 0; i < 2; ++i) {
        const int ra = (4 + 2 * i + wm) * 32 + am;
#pragma unroll
        for (int ks = 0; ks < 4; ++ks)
          af[i][ks] = *(const bf16_8*)&As[b][ra][((2 * ks + ah) ^ rx) * 8];
      }
      // stage: A-h0/B-h0/B-h1 of tile t+2 -> this buffer (last read X(t))
      {
        int T = 2 * it + h + 2; if (T > NTILE - 1) T = NTILE - 1;
        STAGE(T, 0, b); STAGE(T, 3, b); STAGE(T, 1, b);
      }
      __builtin_amdgcn_s_setprio(1);
#pragma unroll
      for (int ks = 0; ks < 4; ++ks) {
#pragma unroll
        for (int i = 0; i < 2; ++i) {
          acc[2 + i][1] = __builtin_amdgcn_mfma_f32_32x32x16_bf16(
              af[i][ks], bfr[1][ks], acc[2 + i][1], 0, 0, 0);
          acc[2 + i][0] = __builtin_amdgcn_mfma_f32_32x32x16_bf16(
              af[i][ks], bfr[0][ks], acc[2 + i][0], 0, 0, 0);
        }
      }
      __builtin_amdgcn_s_setprio(0);
      asm volatile("s_waitcnt vmcnt(6)" ::: "memory");
      __builtin_amdgcn_sched_barrier(0);
      __builtin_amdgcn_s_barrier();
    }
  }
  asm volatile("s_waitcnt vmcnt(0) lgkmcnt(0)" ::: "memory");  // drain dummies

  // C/D layout (32x32): col = lane&31, row = (reg&3) + 8*(reg>>2) + 4*(lane>>5)
  const int cc = am;
  const int rq = ah * 4;
  if (Cb != nullptr) {
#pragma unroll
    for (int im = 0; im < 4; ++im)
#pragma unroll
      for (int in = 0; in < 2; ++in)
#pragma unroll
        for (int reg = 0; reg < 16; ++reg) {
          int row = (reg & 3) + 8 * (reg >> 2) + rq;
          Cb[(size_t)(tm + (2 * im + wm) * 32 + row) * NN +
             (tn + (4 * in + wn) * 32 + cc)] = (__bf16)acc[im][in][reg];
        }
  }

  if (Ctb != nullptr) {
    __syncthreads();
    __bf16 (*Tt)[264] = (__bf16(*)[264])smem;       // 64 x 264 x 2B = 33.8 KB
#pragma unroll
    for (int ch = 0; ch < 4; ++ch) {
      // chunk ch = C cols [ch*64, +64): writers have wn>>1 == ch&1, in = ch>>1
      if ((wn >> 1) == (ch & 1)) {
        const int inw = ch >> 1;
#pragma unroll
        for (int im = 0; im < 4; ++im)
#pragma unroll
          for (int g = 0; g < 4; ++g) {
            bf16_4 v;
#pragma unroll
            for (int r = 0; r < 4; ++r) v[r] = (__bf16)acc[im][inw][g * 4 + r];
            *(bf16_4*)&Tt[(wn & 1) * 32 + cc][(2 * im + wm) * 32 + 8 * g + rq] = v;
          }
      }
      __syncthreads();
#pragma unroll
      for (int rr = 0; rr < 4; ++rr) {
        int trow = rr * 16 + (tid >> 5);
        int tcol = (tid & 31) * 8;
        bf16_8 v = *(const bf16_8*)&Tt[trow][tcol];
        *(bf16_8*)&Ctb[(size_t)(tn + ch * 64 + trow) * NN + tm + tcol] = v;
      }
      __syncthreads();
    }
  }
#undef STAGE
}

// XCD-aware chunked swizzle (T1, r6: FETCH 590->197 MB).

// G1: A2 = A @ A, dual-write (A2, A2t). 512 blocks = 2 clean passes;
// XCD r owns batch r.
__global__ __launch_bounds__(512, 2)
void k_gemm1(const __bf16* __restrict__ Ab, const __bf16* __restrict__ At,
             __bf16* __restrict__ A2, __bf16* __restrict__ A2t) {
  __shared__ __align__(16) __bf16 smem[65536];  // 128 KB static
  int lid = ((int)blockIdx.z * gridDim.y + blockIdx.y) * gridDim.x + blockIdx.x;
  int swz = (lid & 7) * 64 + (lid >> 3);        // 512 blocks
  int bz = swz >> 6, ty = (swz >> 3) & 7, tx = swz & 7;
  size_t mb = (size_t)bz * NN * NN;
  gemm_body256(Ab + mb, At + mb, A2 + mb, A2t + mb, smem, ty, tx);
}

// G2+G3 merged: job0: A3t = At @ A2^T (scalar-C path);
// job1: A4 = A2 @ A2 dual-write (A4, A4t=alias Ab, dead after G1).
// 1024 blocks = 4 passes; XCD r owns batches 2r, 2r+1.
__global__ __launch_bounds__(512, 2)
void k_gemm23(const __bf16* __restrict__ At, const __bf16* __restrict__ A2,
              const __bf16* __restrict__ A2t,
              __bf16* __restrict__ A3t, __bf16* __restrict__ A4,
              __bf16* __restrict__ A4t) {
  __shared__ __align__(16) __bf16 smem[65536];  // 128 KB static
  int lid = ((int)blockIdx.z * gridDim.y + blockIdx.y) * gridDim.x + blockIdx.x;
  int swz = (lid & 7) * 128 + (lid >> 3);       // 1024 blocks
  int bz = swz >> 6, ty = (swz >> 3) & 7, tx = swz & 7;
  int job = bz >> 3;
  size_t mb = (size_t)(bz & 7) * NN * NN;
  if (job == 0)
    gemm_body256(At + mb, A2 + mb, A3t + mb, nullptr, smem, ty, tx);
  else
    gemm_body256(A2 + mb, A2t + mb, A4 + mb, A4t + mb, smem, ty, tx);
}

// One wave per row n. d5=rowdot(A2,A3t), d6=rowdot(A2,A4t),
// d7=rowdot(A4,A3t), d8=rowdot(A4,A4t). d1..d4 free diagonal reads.
__global__ __launch_bounds__(256)
void k_reduce(const float* __restrict__ A, const float* __restrict__ h,
              const __bf16* __restrict__ A2, const __bf16* __restrict__ A3t,
              const __bf16* __restrict__ A4, const __bf16* __restrict__ A4t,
              float* __restrict__ out) {
  int b = blockIdx.y;
  int wave = threadIdx.x >> 6, lane = threadIdx.x & 63;
  int n = blockIdx.x * 4 + wave;
  size_t mb = (size_t)b * NN * NN;
  size_t rb = mb + (size_t)n * NN;
  float d5 = 0, d6 = 0, d7 = 0, d8 = 0;
  for (int c = 0; c < NN; c += 512) {
    int k = c + lane * 8;
    bf16_8 va2  = *(const bf16_8*)(A2 + rb + k);
    bf16_8 va3t = *(const bf16_8*)(A3t + rb + k);
    bf16_8 va4  = *(const bf16_8*)(A4 + rb + k);
    bf16_8 va4t = *(const bf16_8*)(A4t + rb + k);
#pragma unroll
    for (int j = 0; j < 8; ++j) {
      float f2 = (float)va2[j], f4 = (float)va4[j];
      float f3t = (float)va3t[j], f4t = (float)va4t[j];
      d5 += f2 * f3t;
      d6 += f2 * f4t;
      d7 += f4 * f3t;
      d8 += f4 * f4t;
    }
  }
#pragma unroll
  for (int off = 32; off > 0; off >>= 1) {
    d5 += __shfl_xor(d5, off);
    d6 += __shfl_xor(d6, off);
    d7 += __shfl_xor(d7, off);
    d8 += __shfl_xor(d8, off);
  }
  float d1 = A[mb + (size_t)n * NN + n];
  float d2 = (float)A2[rb + n];
  float d3 = (float)A3t[rb + n];
  float d4 = (float)A4[rb + n];
  float r = h[lane] + h[64 + lane] * d1 + h[128 + lane] * d2 + h[192 + lane] * d3 +
            h[256 + lane] * d4 + h[320 + lane] * d5 + h[384 + lane] * d6 +
            h[448 + lane] * d7 + h[512 + lane] * d8;
  out[((size_t)b * NN + n) * NC + lane] = r;
}

extern "C" void kernel_launch(void* const* d_in, const int* in_sizes, int n_in,
                              void* d_out, int out_size, void* d_ws, size_t ws_size,
                              hipStream_t stream) {
  const float* A = (const float*)d_in[0];
  const float* h = (const float*)d_in[1];
  float* out = (float*)d_out;

  size_t elems = (size_t)BB * NN * NN;  // 64 MiB per bf16 buffer
  __bf16* Ab  = (__bf16*)d_ws;
  __bf16* At  = Ab + elems;
  __bf16* A2  = At + elems;
  __bf16* A2t = A2 + elems;
  __bf16* A3t = A2t + elems;
  __bf16* A4  = A3t + elems;
  __bf16* A4t = Ab;  // alias: Ab dead after G1 (total ws: 6 x 64 MiB)

  // A -> bf16 + transpose
  k_convert<<<dim3(32, 32, BB), dim3(256), 0, stream>>>(A, Ab, At);
  // A2 = A @ A  (dual-write)
  k_gemm1<<<dim3(8, 8, BB), dim3(512), 0, stream>>>(Ab, At, A2, A2t);
  // A3t = (A^3)^T and A4 = A2 @ A2 (+A4t) in one dispatch
  k_gemm23<<<dim3(8, 8, 2 * BB), dim3(512), 0, stream>>>(At, A2, A2t, A3t, A4, A4t);
  // diagonals + channel combine
  k_reduce<<<dim3(NN / 4, BB), dim3(256), 0, stream>>>(A, h, A2, A3t, A4, A4t, out);
}